// Round 7
// baseline (345.066 us; speedup 1.0000x reference)
//
#include <hip/hip_runtime.h>

#define NN 32
#define CC 256
#define LL 1024
#define IC 128
#define DA 9216
#define DOUT 131072
#define EPSF 1e-5f

typedef __attribute__((ext_vector_type(8))) short short8;
typedef __attribute__((ext_vector_type(4))) float f32x4;

__device__ __forceinline__ ushort bf_rne(float f) {
  union { float f; unsigned u; } v;
  v.f = f;
  unsigned u = v.u;
  u += 0x7FFF + ((u >> 16) & 1);
  return (ushort)(u >> 16);
}

// pack two fp32 -> packed bf16 pair (lo in [15:0], hi in [31:16]).
// round-half-up (u+0x8000): same 0.5-ULP max error as RNE, 1 add/elem + 1 perm/pair.
__device__ __forceinline__ unsigned bfp2(float lo, float hi) {
  union { float f; unsigned u; } a, b;
  a.f = lo; b.f = hi;
  return __builtin_amdgcn_perm(b.u + 0x8000u, a.u + 0x8000u, 0x07060302u);
}

// ---------------- K_wcvt: weights->bf16 AND zero f/st (memset absorbed) -----
__global__ __launch_bounds__(256) void k_wcvt(const float* __restrict__ wq,
                                              const float* __restrict__ wk,
                                              const float* __restrict__ wo,
                                              ushort* __restrict__ wqkbf,
                                              ushort* __restrict__ wobf,
                                              float* __restrict__ fz) {
  int b = blockIdx.x;
  if (b < 96) {
    int idx = (b * 256 + threadIdx.x) * 4;  // 98304 elems
    float4 v;
    if (idx < 32768) v = *(const float4*)(wq + idx);
    else if (idx < 65536) v = *(const float4*)(wk + idx - 32768);
    else v = *(const float4*)(wo + idx - 65536);
    uint2 o;
    o.x = bfp2(v.x, v.y);
    o.y = bfp2(v.z, v.w);
    if (idx < 65536) *(uint2*)(wqkbf + idx) = o;
    else *(uint2*)(wobf + idx - 65536) = o;
  } else {
    int idx = ((b - 96) * 256 + threadIdx.x) * 4;  // zero f(294912)+st(64)
    if (idx < 294976)
      *(float4*)(fz + idx) = make_float4(0.f, 0.f, 0.f, 0.f);
  }
}

// ---------------- K_qkx: fused transpose + q/k MFMA -------------------------
// grid (16 l-tiles of 64, 32 n), 256 thr = 4 waves. LDS x-tile bf16 [l][264].
__global__ __launch_bounds__(256, 4) void k_qkx(const float* __restrict__ x,
                                                const ushort* __restrict__ wqkbf,
                                                float* __restrict__ q,
                                                float* __restrict__ k) {
  __shared__ ushort xl[64 * 264];  // 33.8 KB
  int t = threadIdx.x;
  int n = blockIdx.y;
  int l0 = blockIdx.x * 64;
  int lane = t & 63, wv = t >> 6;
  int m16 = lane & 15, kg = lane >> 4;

  // stage x[c][l0..l0+64) -> xl[l][c] bf16, 8 c's packed per b128 write
  {
    int l = t & 63, g = t >> 6;
    const float* xn = x + ((size_t)n * CC) * LL + l0 + l;
#pragma unroll
    for (int i = 0; i < 8; i++) {
      int c8 = (i * 4 + g) * 8;
      float v[8];
#pragma unroll
      for (int j = 0; j < 8; j++) v[j] = xn[(size_t)(c8 + j) * LL];
      union { short8 s; unsigned u[4]; } p;
      p.u[0] = bfp2(v[0], v[1]);
      p.u[1] = bfp2(v[2], v[3]);
      p.u[2] = bfp2(v[4], v[5]);
      p.u[3] = bfp2(v[6], v[7]);
      *(short8*)&xl[l * 264 + c8] = p.s;
    }
  }
  __syncthreads();

  f32x4 acc[2][2][4];
#pragma unroll
  for (int mt = 0; mt < 2; mt++)
#pragma unroll
    for (int ms = 0; ms < 2; ms++)
#pragma unroll
      for (int ls = 0; ls < 4; ls++) acc[mt][ms][ls] = (f32x4){0.f, 0.f, 0.f, 0.f};

#pragma unroll
  for (int kc = 0; kc < 8; kc++) {
    short8 a[2][2];
#pragma unroll
    for (int mt = 0; mt < 2; mt++)
#pragma unroll
      for (int ms = 0; ms < 2; ms++)
        a[mt][ms] = *(const short8*)(wqkbf +
            (((mt * 128 + wv * 32 + ms * 16 + m16) << 8) + kc * 32 + kg * 8));
#pragma unroll
    for (int ls = 0; ls < 4; ls++) {
      short8 b = *(const short8*)&xl[(ls * 16 + m16) * 264 + kc * 32 + kg * 8];
      acc[0][0][ls] =
          __builtin_amdgcn_mfma_f32_16x16x32_bf16(a[0][0], b, acc[0][0][ls], 0, 0, 0);
      acc[0][1][ls] =
          __builtin_amdgcn_mfma_f32_16x16x32_bf16(a[0][1], b, acc[0][1][ls], 0, 0, 0);
      acc[1][0][ls] =
          __builtin_amdgcn_mfma_f32_16x16x32_bf16(a[1][0], b, acc[1][0][ls], 0, 0, 0);
      acc[1][1][ls] =
          __builtin_amdgcn_mfma_f32_16x16x32_bf16(a[1][1], b, acc[1][1][ls], 0, 0, 0);
    }
  }

#pragma unroll
  for (int mt = 0; mt < 2; mt++) {
    float* outp = (mt ? k : q) + (size_t)n * IC * LL;
#pragma unroll
    for (int ms = 0; ms < 2; ms++)
#pragma unroll
      for (int ls = 0; ls < 4; ls++) {
        int col = l0 + ls * 16 + m16;
#pragma unroll
        for (int r = 0; r < 4; r++)
          outp[(size_t)(wv * 32 + ms * 16 + kg * 4 + r) * LL + col] =
              acc[mt][ms][ls][r];
      }
  }
}

// ---------------- K2: local 3x3 attention scores, f2 += 2*(q.k_patch) -------
__global__ __launch_bounds__(256) void k_attn(const float* __restrict__ q,
                                              const float* __restrict__ k,
                                              float* __restrict__ f2) {
  int n = blockIdx.x;
  int c0 = blockIdx.y * 32;
  int l = blockIdx.z * 256 + threadIdx.x;
  int h = l >> 5, w = l & 31;
  const float* qn = q + (size_t)n * IC * LL;
  const float* kn = k + (size_t)n * IC * LL;
  bool val[9];
  int off[9];
#pragma unroll
  for (int i = 0; i < 3; i++)
#pragma unroll
    for (int j = 0; j < 3; j++) {
      int r = i * 3 + j;
      int hh = h + i - 1, ww = w + j - 1;
      val[r] = (hh >= 0 && hh < 32 && ww >= 0 && ww < 32);
      off[r] = hh * 32 + ww;
    }
  float acc[9];
#pragma unroll
  for (int r = 0; r < 9; r++) acc[r] = 0.f;
#pragma unroll 4
  for (int cc = 0; cc < 32; cc++) {
    int c = c0 + cc;
    float qv = qn[c * LL + l];
    const float* kc = kn + c * LL;
#pragma unroll
    for (int r = 0; r < 9; r++) {
      float kv = val[r] ? kc[off[r]] : 0.f;
      acc[r] += qv * kv;
    }
  }
#pragma unroll
  for (int r = 0; r < 9; r++)
    atomicAdd(&f2[(size_t)n * DA + r * LL + l], 2.f * acc[r]);
}

// ---------------- K3: LayerNorm over 9216, in place -------------------------
__global__ __launch_bounds__(256) void k_ln1(float* __restrict__ f2,
                                             const float* __restrict__ g1,
                                             const float* __restrict__ b1) {
  int n = blockIdx.x, t = threadIdx.x;
  float* row = f2 + (size_t)n * DA;
  float4 v[9];
  float s = 0.f, ss = 0.f;
#pragma unroll
  for (int kk = 0; kk < 9; kk++) {
    v[kk] = ((const float4*)row)[t + kk * 256];
    s += v[kk].x + v[kk].y + v[kk].z + v[kk].w;
    ss += v[kk].x * v[kk].x + v[kk].y * v[kk].y + v[kk].z * v[kk].z +
          v[kk].w * v[kk].w;
  }
#pragma unroll
  for (int o = 32; o; o >>= 1) {
    s += __shfl_down(s, o);
    ss += __shfl_down(ss, o);
  }
  __shared__ float ps[4], pss[4], stats[2];
  int wid = t >> 6, lid = t & 63;
  if (lid == 0) { ps[wid] = s; pss[wid] = ss; }
  __syncthreads();
  if (t == 0) {
    float S = ps[0] + ps[1] + ps[2] + ps[3];
    float SS = pss[0] + pss[1] + pss[2] + pss[3];
    float mu = S / DA;
    float var = SS / DA - mu * mu;
    stats[0] = mu;
    stats[1] = rsqrtf(var + EPSF);
  }
  __syncthreads();
  float mu = stats[0], rs = stats[1];
#pragma unroll
  for (int kk = 0; kk < 9; kk++) {
    float4 g = ((const float4*)g1)[t + kk * 256];
    float4 b = ((const float4*)b1)[t + kk * 256];
    float4 o;
    o.x = (v[kk].x - mu) * rs * g.x + b.x;
    o.y = (v[kk].y - mu) * rs * g.y + b.y;
    o.z = (v[kk].z - mu) * rs * g.z + b.z;
    o.w = (v[kk].w - mu) * rs * g.w + b.w;
    ((float4*)row)[t + kk * 256] = o;
  }
}

// ---------------- K4: h1 = relu(fln @ w1^T + b1) -> bf16, 16 n per block ----
__global__ __launch_bounds__(256) void k_ffn1(const float* __restrict__ fln,
                                              const float* __restrict__ w1,
                                              const float* __restrict__ b1,
                                              ushort* __restrict__ h1bf) {
  int o = blockIdx.x, nsb = blockIdx.y * 16, t = threadIdx.x;
  float acc[16];
#pragma unroll
  for (int i = 0; i < 16; i++) acc[i] = 0.f;
  const float4* w1r = (const float4*)(w1 + (size_t)o * DA);
  for (int kk = 0; kk < 9; kk++) {
    float4 wv = w1r[t + kk * 256];
#pragma unroll
    for (int i = 0; i < 16; i++) {
      float4 fv = ((const float4*)(fln + (size_t)(nsb + i) * DA))[t + kk * 256];
      acc[i] += wv.x * fv.x + wv.y * fv.y + wv.z * fv.z + wv.w * fv.w;
    }
  }
#pragma unroll
  for (int i = 0; i < 16; i++)
#pragma unroll
    for (int s = 32; s; s >>= 1) acc[i] += __shfl_down(acc[i], s);
  __shared__ float part[4][16];
  int wid = t >> 6, lid = t & 63;
  if (lid == 0) {
#pragma unroll
    for (int i = 0; i < 16; i++) part[wid][i] = acc[i];
  }
  __syncthreads();
  if (t < 16) {
    float sum = part[0][t] + part[1][t] + part[2][t] + part[3][t] + b1[o];
    h1bf[(size_t)(nsb + t) * CC + o] = bf_rne(fmaxf(sum, 0.f));
  }
}

// ---------------- K5: h2 = h1 @ w2^T + b2 via bf16 MFMA ---------------------
// grid 1024 (j-tiles of 128), 4 waves -> 4 blocks/CU, 16 waves/CU.
// Wave = 32 j x 32 n: acc[2][2], 32 MFMA. perm-pack conversion (12 VALU/frag).
// 1-deep w2 prefetch. Stats atomically into st (zeroed by k_wcvt).
__global__ __launch_bounds__(256, 4) void k_ffn2(
    const ushort* __restrict__ h1bf, const float* __restrict__ w2,
    const float* __restrict__ b2, float* __restrict__ h2,
    float* __restrict__ st) {
  __shared__ float bs[64];
  int t = threadIdx.x;
  int lane = t & 63, wv = t >> 6;
  int m16 = lane & 15, kg = lane >> 4;
  int j0 = blockIdx.x * 128 + wv * 32;
  if (t < 64) bs[t] = 0.f;

  int j[2] = {j0 + m16, j0 + 16 + m16};

  f32x4 acc[2][2];
#pragma unroll
  for (int m = 0; m < 2; m++)
#pragma unroll
    for (int nn = 0; nn < 2; nn++) acc[m][nn] = (f32x4){0.f, 0.f, 0.f, 0.f};

  float4 lo[2], hi[2];
#pragma unroll
  for (int nn = 0; nn < 2; nn++) {
    const float* src = w2 + (size_t)j[nn] * CC + kg * 8;
    lo[nn] = *(const float4*)src;
    hi[nn] = *(const float4*)(src + 4);
  }

#pragma unroll
  for (int kc = 0; kc < 8; kc++) {
    short8 a0 = *(const short8*)(h1bf + m16 * CC + kc * 32 + kg * 8);
    short8 a1 = *(const short8*)(h1bf + (16 + m16) * CC + kc * 32 + kg * 8);
    short8 bf[2];
#pragma unroll
    for (int nn = 0; nn < 2; nn++) {
      union { short8 s; unsigned u[4]; } cv;
      cv.u[0] = bfp2(lo[nn].x, lo[nn].y);
      cv.u[1] = bfp2(lo[nn].z, lo[nn].w);
      cv.u[2] = bfp2(hi[nn].x, hi[nn].y);
      cv.u[3] = bfp2(hi[nn].z, hi[nn].w);
      bf[nn] = cv.s;
    }
    if (kc < 7) {
#pragma unroll
      for (int nn = 0; nn < 2; nn++) {
        const float* src = w2 + (size_t)j[nn] * CC + (kc + 1) * 32 + kg * 8;
        lo[nn] = *(const float4*)src;
        hi[nn] = *(const float4*)(src + 4);
      }
    }
#pragma unroll
    for (int nn = 0; nn < 2; nn++) {
      acc[0][nn] =
          __builtin_amdgcn_mfma_f32_16x16x32_bf16(a0, bf[nn], acc[0][nn], 0, 0, 0);
      acc[1][nn] =
          __builtin_amdgcn_mfma_f32_16x16x32_bf16(a1, bf[nn], acc[1][nn], 0, 0, 0);
    }
  }
  __syncthreads();  // bs zero-init visible before LDS atomics

  float b2v[2] = {b2[j[0]], b2[j[1]]};

  float s8[2][4], q8[2][4];
#pragma unroll
  for (int m = 0; m < 2; m++)
#pragma unroll
    for (int r = 0; r < 4; r++) { s8[m][r] = 0.f; q8[m][r] = 0.f; }
#pragma unroll
  for (int m = 0; m < 2; m++)
#pragma unroll
    for (int nn = 0; nn < 2; nn++) {
#pragma unroll
      for (int r = 0; r < 4; r++) {
        float v = acc[m][nn][r] + b2v[nn];
        int row = m * 16 + kg * 4 + r;
        h2[(size_t)row * DOUT + j[nn]] = v;
        s8[m][r] += v;
        q8[m][r] += v * v;
      }
    }
#pragma unroll
  for (int off = 8; off; off >>= 1)
#pragma unroll
    for (int m = 0; m < 2; m++)
#pragma unroll
      for (int r = 0; r < 4; r++) {
        s8[m][r] += __shfl_down(s8[m][r], off, 16);
        q8[m][r] += __shfl_down(q8[m][r], off, 16);
      }
  if (m16 == 0) {
#pragma unroll
    for (int m = 0; m < 2; m++)
#pragma unroll
      for (int r = 0; r < 4; r++) {
        int row = m * 16 + kg * 4 + r;
        atomicAdd(&bs[row], s8[m][r]);
        atomicAdd(&bs[32 + row], q8[m][r]);
      }
  }
  __syncthreads();
  if (t < 64) atomicAdd(&st[t], bs[t]);
}

// ---------------- K7: out = BN(LN2(h2)*g2+b2 @ w_out^T) + x via MFMA --------
// R7 FIX: grid (32 l-tiles of 32, 32 n), 4 waves. Each wave = O-QUARTER
// (64 ch, wv*64) x ALL 32 l (2 ls-frags) -> full 256-channel coverage
// (R5/R6 bug: Og=wv&1 covered only 128 channels). 32 MFMA/wave, acc[4][2].
__global__ __launch_bounds__(256, 4) void k_out(
    const float* __restrict__ h2, const float* __restrict__ st,
    const float* __restrict__ g2, const float* __restrict__ b2,
    const ushort* __restrict__ wobf, const float* __restrict__ bn_g,
    const float* __restrict__ bn_b, const float* __restrict__ bn_m,
    const float* __restrict__ bn_v, const float* __restrict__ x,
    float* __restrict__ out) {
  __shared__ ushort yl[32 * 136];  // 8.5 KB
  int t = threadIdx.x;
  int n = blockIdx.y;
  int l0 = blockIdx.x * 32;
  float mu = st[n] * (1.f / DOUT);
  float rs = rsqrtf(st[32 + n] * (1.f / DOUT) - mu * mu + EPSF);

  {
    int l = t & 31, og = t >> 5;  // 8 o-groups of 16
    const float* h2n = h2 + (size_t)n * DOUT;
#pragma unroll
    for (int half = 0; half < 2; half++) {
      float y[8];
#pragma unroll
      for (int jj = 0; jj < 8; jj++) {
        int o = og * 16 + half * 8 + jj;
        int d = o * LL + l0 + l;
        y[jj] = (h2n[d] - mu) * rs * g2[d] + b2[d];
      }
      union { short8 s; unsigned u[4]; } p;
      p.u[0] = bfp2(y[0], y[1]);
      p.u[1] = bfp2(y[2], y[3]);
      p.u[2] = bfp2(y[4], y[5]);
      p.u[3] = bfp2(y[6], y[7]);
      *(short8*)&yl[l * 136 + og * 16 + half * 8] = p.s;
    }
  }
  __syncthreads();

  int lane = t & 63, wv = t >> 6;
  int m16 = lane & 15, kg = lane >> 4;
  f32x4 acc[4][2];
#pragma unroll
  for (int ms = 0; ms < 4; ms++)
#pragma unroll
    for (int ls = 0; ls < 2; ls++) acc[ms][ls] = (f32x4){0.f, 0.f, 0.f, 0.f};

#pragma unroll
  for (int kc = 0; kc < 4; kc++) {
    short8 b[2];
#pragma unroll
    for (int ls = 0; ls < 2; ls++)
      b[ls] = *(const short8*)&yl[(ls * 16 + m16) * 136 + kc * 32 + kg * 8];
#pragma unroll
    for (int ms = 0; ms < 4; ms++) {
      short8 a = *(const short8*)(wobf +
          (((wv * 64 + ms * 16 + m16) << 7) + kc * 32 + kg * 8));
#pragma unroll
      for (int ls = 0; ls < 2; ls++)
        acc[ms][ls] =
            __builtin_amdgcn_mfma_f32_16x16x32_bf16(a, b[ls], acc[ms][ls], 0, 0, 0);
    }
  }

#pragma unroll
  for (int ms = 0; ms < 4; ms++)
#pragma unroll
    for (int r = 0; r < 4; r++) {
      int O = wv * 64 + ms * 16 + kg * 4 + r;
      float sc = bn_g[O] * rsqrtf(bn_v[O] + EPSF);
      float sh = bn_b[O] - bn_m[O] * sc;
#pragma unroll
      for (int ls = 0; ls < 2; ls++) {
        int col = l0 + ls * 16 + m16;
        size_t base = ((size_t)(n * CC + O)) * LL + col;
        out[base] = acc[ms][ls][r] * sc + sh + x[base];
      }
    }
}

extern "C" void kernel_launch(void* const* d_in, const int* in_sizes, int n_in,
                              void* d_out, int out_size, void* d_ws,
                              size_t ws_size, hipStream_t stream) {
  const float* x = (const float*)d_in[0];
  const float* wq = (const float*)d_in[1];
  const float* wk = (const float*)d_in[2];
  const float* gamma1 = (const float*)d_in[3];
  const float* beta1 = (const float*)d_in[4];
  const float* w1 = (const float*)d_in[5];
  const float* b1 = (const float*)d_in[6];
  const float* w2 = (const float*)d_in[7];
  const float* b2 = (const float*)d_in[8];
  const float* gamma2 = (const float*)d_in[9];
  const float* beta2 = (const float*)d_in[10];
  const float* w_out = (const float*)d_in[11];
  const float* bn_g = (const float*)d_in[12];
  const float* bn_b = (const float*)d_in[13];
  const float* bn_m = (const float*)d_in[14];
  const float* bn_v = (const float*)d_in[15];
  float* outp = (float*)d_out;
  float* ws = (float*)d_ws;

  // ws layout (floats): q(4194304) | k(4194304) | f(294912) | st(64) |
  //   h1bf(4096) | wqkbf(32768) | wobf(16384). h2 aliases q.
  float* qb = ws;
  float* kb = ws + 4194304;
  float* fb = ws + 8388608;
  float* stb = ws + 8683520;
  ushort* h1bfb = (ushort*)(ws + 8683584);
  ushort* wqkbfb = (ushort*)(ws + 8687680);
  ushort* wobfb = (ushort*)(ws + 8720448);
  float* h2b = qb;

  if (ws_size < 8736832ull * sizeof(float)) return;  // fail visibly

  // k_wcvt converts weights AND zeroes f+st (memset dispatch absorbed)
  k_wcvt<<<dim3(385), 256, 0, stream>>>(wq, wk, w_out, wqkbfb, wobfb, fb);
  k_qkx<<<dim3(16, 32), 256, 0, stream>>>(x, wqkbfb, qb, kb);
  k_attn<<<dim3(32, 4, 4), 256, 0, stream>>>(qb, kb, fb);
  k_ln1<<<dim3(32), 256, 0, stream>>>(fb, gamma1, beta1);
  k_ffn1<<<dim3(256, 2), 256, 0, stream>>>(fb, w1, b1, h1bfb);
  k_ffn2<<<dim3(1024), 256, 0, stream>>>(h1bfb, w2, b2, h2b, stb);
  k_out<<<dim3(32, 32), 256, 0, stream>>>(h2b, stb, gamma2, beta2, wobfb,
                                          bn_g, bn_b, bn_m, bn_v, x, outp);
}

// Round 8
// 343.071 us; speedup vs baseline: 1.0058x; 1.0058x over previous
//
#include <hip/hip_runtime.h>

#define NN 32
#define CC 256
#define LL 1024
#define IC 128
#define DA 9216
#define DOUT 131072
#define EPSF 1e-5f

typedef __attribute__((ext_vector_type(8))) short short8;
typedef __attribute__((ext_vector_type(4))) float f32x4;

__device__ __forceinline__ ushort bf_rne(float f) {
  union { float f; unsigned u; } v;
  v.f = f;
  unsigned u = v.u;
  u += 0x7FFF + ((u >> 16) & 1);
  return (ushort)(u >> 16);
}

// pack two fp32 -> packed bf16 pair (lo in [15:0], hi in [31:16]).
// round-half-up (u+0x8000): same 0.5-ULP max error as RNE, 1 add/elem + 1 perm/pair.
__device__ __forceinline__ unsigned bfp2(float lo, float hi) {
  union { float f; unsigned u; } a, b;
  a.f = lo; b.f = hi;
  return __builtin_amdgcn_perm(b.u + 0x8000u, a.u + 0x8000u, 0x07060302u);
}

// ---------------- K_wcvt: weights->bf16 AND zero f/st (memset absorbed) -----
__global__ __launch_bounds__(256) void k_wcvt(const float* __restrict__ wq,
                                              const float* __restrict__ wk,
                                              const float* __restrict__ wo,
                                              ushort* __restrict__ wqkbf,
                                              ushort* __restrict__ wobf,
                                              float* __restrict__ fz) {
  int b = blockIdx.x;
  if (b < 96) {
    int idx = (b * 256 + threadIdx.x) * 4;  // 98304 elems
    float4 v;
    if (idx < 32768) v = *(const float4*)(wq + idx);
    else if (idx < 65536) v = *(const float4*)(wk + idx - 32768);
    else v = *(const float4*)(wo + idx - 65536);
    uint2 o;
    o.x = bfp2(v.x, v.y);
    o.y = bfp2(v.z, v.w);
    if (idx < 65536) *(uint2*)(wqkbf + idx) = o;
    else *(uint2*)(wobf + idx - 65536) = o;
  } else {
    int idx = ((b - 96) * 256 + threadIdx.x) * 4;  // zero f(294912)+st(64)
    if (idx < 294976)
      *(float4*)(fz + idx) = make_float4(0.f, 0.f, 0.f, 0.f);
  }
}

// ---------------- K_qkx: fused transpose + q/k MFMA -------------------------
// grid (16 l-tiles of 64, 32 n), 256 thr = 4 waves. LDS x-tile bf16 [l][264].
__global__ __launch_bounds__(256, 4) void k_qkx(const float* __restrict__ x,
                                                const ushort* __restrict__ wqkbf,
                                                float* __restrict__ q,
                                                float* __restrict__ k) {
  __shared__ ushort xl[64 * 264];  // 33.8 KB
  int t = threadIdx.x;
  int n = blockIdx.y;
  int l0 = blockIdx.x * 64;
  int lane = t & 63, wv = t >> 6;
  int m16 = lane & 15, kg = lane >> 4;

  // stage x[c][l0..l0+64) -> xl[l][c] bf16, 8 c's packed per b128 write
  {
    int l = t & 63, g = t >> 6;
    const float* xn = x + ((size_t)n * CC) * LL + l0 + l;
#pragma unroll
    for (int i = 0; i < 8; i++) {
      int c8 = (i * 4 + g) * 8;
      float v[8];
#pragma unroll
      for (int j = 0; j < 8; j++) v[j] = xn[(size_t)(c8 + j) * LL];
      union { short8 s; unsigned u[4]; } p;
      p.u[0] = bfp2(v[0], v[1]);
      p.u[1] = bfp2(v[2], v[3]);
      p.u[2] = bfp2(v[4], v[5]);
      p.u[3] = bfp2(v[6], v[7]);
      *(short8*)&xl[l * 264 + c8] = p.s;
    }
  }
  __syncthreads();

  f32x4 acc[2][2][4];
#pragma unroll
  for (int mt = 0; mt < 2; mt++)
#pragma unroll
    for (int ms = 0; ms < 2; ms++)
#pragma unroll
      for (int ls = 0; ls < 4; ls++) acc[mt][ms][ls] = (f32x4){0.f, 0.f, 0.f, 0.f};

#pragma unroll
  for (int kc = 0; kc < 8; kc++) {
    short8 a[2][2];
#pragma unroll
    for (int mt = 0; mt < 2; mt++)
#pragma unroll
      for (int ms = 0; ms < 2; ms++)
        a[mt][ms] = *(const short8*)(wqkbf +
            (((mt * 128 + wv * 32 + ms * 16 + m16) << 8) + kc * 32 + kg * 8));
#pragma unroll
    for (int ls = 0; ls < 4; ls++) {
      short8 b = *(const short8*)&xl[(ls * 16 + m16) * 264 + kc * 32 + kg * 8];
      acc[0][0][ls] =
          __builtin_amdgcn_mfma_f32_16x16x32_bf16(a[0][0], b, acc[0][0][ls], 0, 0, 0);
      acc[0][1][ls] =
          __builtin_amdgcn_mfma_f32_16x16x32_bf16(a[0][1], b, acc[0][1][ls], 0, 0, 0);
      acc[1][0][ls] =
          __builtin_amdgcn_mfma_f32_16x16x32_bf16(a[1][0], b, acc[1][0][ls], 0, 0, 0);
      acc[1][1][ls] =
          __builtin_amdgcn_mfma_f32_16x16x32_bf16(a[1][1], b, acc[1][1][ls], 0, 0, 0);
    }
  }

#pragma unroll
  for (int mt = 0; mt < 2; mt++) {
    float* outp = (mt ? k : q) + (size_t)n * IC * LL;
#pragma unroll
    for (int ms = 0; ms < 2; ms++)
#pragma unroll
      for (int ls = 0; ls < 4; ls++) {
        int col = l0 + ls * 16 + m16;
#pragma unroll
        for (int r = 0; r < 4; r++)
          outp[(size_t)(wv * 32 + ms * 16 + kg * 4 + r) * LL + col] =
              acc[mt][ms][ls][r];
      }
  }
}

// ---------------- K2: local 3x3 attention scores, f2 += 2*(q.k_patch) -------
__global__ __launch_bounds__(256) void k_attn(const float* __restrict__ q,
                                              const float* __restrict__ k,
                                              float* __restrict__ f2) {
  int n = blockIdx.x;
  int c0 = blockIdx.y * 32;
  int l = blockIdx.z * 256 + threadIdx.x;
  int h = l >> 5, w = l & 31;
  const float* qn = q + (size_t)n * IC * LL;
  const float* kn = k + (size_t)n * IC * LL;
  bool val[9];
  int off[9];
#pragma unroll
  for (int i = 0; i < 3; i++)
#pragma unroll
    for (int j = 0; j < 3; j++) {
      int r = i * 3 + j;
      int hh = h + i - 1, ww = w + j - 1;
      val[r] = (hh >= 0 && hh < 32 && ww >= 0 && ww < 32);
      off[r] = hh * 32 + ww;
    }
  float acc[9];
#pragma unroll
  for (int r = 0; r < 9; r++) acc[r] = 0.f;
#pragma unroll 4
  for (int cc = 0; cc < 32; cc++) {
    int c = c0 + cc;
    float qv = qn[c * LL + l];
    const float* kc = kn + c * LL;
#pragma unroll
    for (int r = 0; r < 9; r++) {
      float kv = val[r] ? kc[off[r]] : 0.f;
      acc[r] += qv * kv;
    }
  }
#pragma unroll
  for (int r = 0; r < 9; r++)
    atomicAdd(&f2[(size_t)n * DA + r * LL + l], 2.f * acc[r]);
}

// ---------------- K3: LayerNorm over 9216, in place -------------------------
__global__ __launch_bounds__(256) void k_ln1(float* __restrict__ f2,
                                             const float* __restrict__ g1,
                                             const float* __restrict__ b1) {
  int n = blockIdx.x, t = threadIdx.x;
  float* row = f2 + (size_t)n * DA;
  float4 v[9];
  float s = 0.f, ss = 0.f;
#pragma unroll
  for (int kk = 0; kk < 9; kk++) {
    v[kk] = ((const float4*)row)[t + kk * 256];
    s += v[kk].x + v[kk].y + v[kk].z + v[kk].w;
    ss += v[kk].x * v[kk].x + v[kk].y * v[kk].y + v[kk].z * v[kk].z +
          v[kk].w * v[kk].w;
  }
#pragma unroll
  for (int o = 32; o; o >>= 1) {
    s += __shfl_down(s, o);
    ss += __shfl_down(ss, o);
  }
  __shared__ float ps[4], pss[4], stats[2];
  int wid = t >> 6, lid = t & 63;
  if (lid == 0) { ps[wid] = s; pss[wid] = ss; }
  __syncthreads();
  if (t == 0) {
    float S = ps[0] + ps[1] + ps[2] + ps[3];
    float SS = pss[0] + pss[1] + pss[2] + pss[3];
    float mu = S / DA;
    float var = SS / DA - mu * mu;
    stats[0] = mu;
    stats[1] = rsqrtf(var + EPSF);
  }
  __syncthreads();
  float mu = stats[0], rs = stats[1];
#pragma unroll
  for (int kk = 0; kk < 9; kk++) {
    float4 g = ((const float4*)g1)[t + kk * 256];
    float4 b = ((const float4*)b1)[t + kk * 256];
    float4 o;
    o.x = (v[kk].x - mu) * rs * g.x + b.x;
    o.y = (v[kk].y - mu) * rs * g.y + b.y;
    o.z = (v[kk].z - mu) * rs * g.z + b.z;
    o.w = (v[kk].w - mu) * rs * g.w + b.w;
    ((float4*)row)[t + kk * 256] = o;
  }
}

// ---------------- K4: h1 = relu(fln @ w1^T + b1) -> bf16, 16 n per block ----
__global__ __launch_bounds__(256) void k_ffn1(const float* __restrict__ fln,
                                              const float* __restrict__ w1,
                                              const float* __restrict__ b1,
                                              ushort* __restrict__ h1bf) {
  int o = blockIdx.x, nsb = blockIdx.y * 16, t = threadIdx.x;
  float acc[16];
#pragma unroll
  for (int i = 0; i < 16; i++) acc[i] = 0.f;
  const float4* w1r = (const float4*)(w1 + (size_t)o * DA);
  for (int kk = 0; kk < 9; kk++) {
    float4 wv = w1r[t + kk * 256];
#pragma unroll
    for (int i = 0; i < 16; i++) {
      float4 fv = ((const float4*)(fln + (size_t)(nsb + i) * DA))[t + kk * 256];
      acc[i] += wv.x * fv.x + wv.y * fv.y + wv.z * fv.z + wv.w * fv.w;
    }
  }
#pragma unroll
  for (int i = 0; i < 16; i++)
#pragma unroll
    for (int s = 32; s; s >>= 1) acc[i] += __shfl_down(acc[i], s);
  __shared__ float part[4][16];
  int wid = t >> 6, lid = t & 63;
  if (lid == 0) {
#pragma unroll
    for (int i = 0; i < 16; i++) part[wid][i] = acc[i];
  }
  __syncthreads();
  if (t < 16) {
    float sum = part[0][t] + part[1][t] + part[2][t] + part[3][t] + b1[o];
    h1bf[(size_t)(nsb + t) * CC + o] = bf_rne(fmaxf(sum, 0.f));
  }
}

// ---------------- K5: h2 = h1 @ w2^T + b2 via bf16 MFMA ---------------------
// R8 REWRITE: coalesced LDS staging. R7 counters showed 79.5us at VALU 3% /
// MFMA 1% / VGPR 32: per-lane row-strided w2 loads (rows 1KB apart within one
// instruction) + compiler-serialized prefetch = pure latency stall.
// Now: block stages its full 128-row x 256-col w2 tile into LDS bf16
// (67.6 KB, 2 blocks/CU). Staging reads CONTIGUOUS 4KB slabs (thread t ->
// +i*1024+t*4), 8 float4 in flight per thread; one barrier; MFMA loop reads
// B-frags from LDS only. Grid 1024, 4 waves; wave = 32j x 32n, acc[2][2].
__global__ __launch_bounds__(256, 2) void k_ffn2(
    const ushort* __restrict__ h1bf, const float* __restrict__ w2,
    const float* __restrict__ b2, float* __restrict__ h2,
    float* __restrict__ st) {
  __shared__ ushort wt[128 * 264];  // 67.6 KB
  __shared__ float bs[64];
  int t = threadIdx.x;
  int j0 = blockIdx.x * 128;
  if (t < 64) bs[t] = 0.f;

  // ---- stage: w2[j0+row][0..256) -> wt[row][col] bf16, coalesced ----
  {
    const float* wsrc = w2 + (size_t)j0 * CC;
    int row_t = t >> 6;          // 0..3
    int col_t = (t & 63) * 4;    // 0..252
#pragma unroll
    for (int io = 0; io < 4; io++) {
      float4 v[8];
#pragma unroll
      for (int u = 0; u < 8; u++)
        v[u] = *(const float4*)(wsrc + (size_t)(io * 8 + u) * 1024 + t * 4);
#pragma unroll
      for (int u = 0; u < 8; u++) {
        int row = (io * 8 + u) * 4 + row_t;
        uint2 p;
        p.x = bfp2(v[u].x, v[u].y);
        p.y = bfp2(v[u].z, v[u].w);
        *(uint2*)&wt[row * 264 + col_t] = p;
      }
    }
  }
  __syncthreads();  // wt ready; also makes bs zero-init visible

  int lane = t & 63, wv = t >> 6;
  int m16 = lane & 15, kg = lane >> 4;
  int jw = j0 + wv * 32;
  int j[2] = {jw + m16, jw + 16 + m16};

  f32x4 acc[2][2];
#pragma unroll
  for (int m = 0; m < 2; m++)
#pragma unroll
    for (int nn = 0; nn < 2; nn++) acc[m][nn] = (f32x4){0.f, 0.f, 0.f, 0.f};

#pragma unroll
  for (int kc = 0; kc < 8; kc++) {
    short8 a0 = *(const short8*)(h1bf + m16 * CC + kc * 32 + kg * 8);
    short8 a1 = *(const short8*)(h1bf + (16 + m16) * CC + kc * 32 + kg * 8);
#pragma unroll
    for (int nn = 0; nn < 2; nn++) {
      short8 b = *(const short8*)&wt[(wv * 32 + nn * 16 + m16) * 264 +
                                     kc * 32 + kg * 8];
      acc[0][nn] =
          __builtin_amdgcn_mfma_f32_16x16x32_bf16(a0, b, acc[0][nn], 0, 0, 0);
      acc[1][nn] =
          __builtin_amdgcn_mfma_f32_16x16x32_bf16(a1, b, acc[1][nn], 0, 0, 0);
    }
  }

  float b2v[2] = {b2[j[0]], b2[j[1]]};

  float s8[2][4], q8[2][4];
#pragma unroll
  for (int m = 0; m < 2; m++)
#pragma unroll
    for (int r = 0; r < 4; r++) { s8[m][r] = 0.f; q8[m][r] = 0.f; }
#pragma unroll
  for (int m = 0; m < 2; m++)
#pragma unroll
    for (int nn = 0; nn < 2; nn++) {
#pragma unroll
      for (int r = 0; r < 4; r++) {
        float v = acc[m][nn][r] + b2v[nn];
        int row = m * 16 + kg * 4 + r;
        h2[(size_t)row * DOUT + j[nn]] = v;
        s8[m][r] += v;
        q8[m][r] += v * v;
      }
    }
#pragma unroll
  for (int off = 8; off; off >>= 1)
#pragma unroll
    for (int m = 0; m < 2; m++)
#pragma unroll
      for (int r = 0; r < 4; r++) {
        s8[m][r] += __shfl_down(s8[m][r], off, 16);
        q8[m][r] += __shfl_down(q8[m][r], off, 16);
      }
  if (m16 == 0) {
#pragma unroll
    for (int m = 0; m < 2; m++)
#pragma unroll
      for (int r = 0; r < 4; r++) {
        int row = m * 16 + kg * 4 + r;
        atomicAdd(&bs[row], s8[m][r]);
        atomicAdd(&bs[32 + row], q8[m][r]);
      }
  }
  __syncthreads();
  if (t < 64) atomicAdd(&st[t], bs[t]);
}

// ---------------- K7: out = BN(LN2(h2)*g2+b2 @ w_out^T) + x via MFMA --------
// grid (32 l-tiles of 32, 32 n), 4 waves. Each wave = O-quarter (64 ch) x
// all 32 l (2 ls-frags) -> full 256-channel coverage. 32 MFMA/wave, acc[4][2].
__global__ __launch_bounds__(256, 4) void k_out(
    const float* __restrict__ h2, const float* __restrict__ st,
    const float* __restrict__ g2, const float* __restrict__ b2,
    const ushort* __restrict__ wobf, const float* __restrict__ bn_g,
    const float* __restrict__ bn_b, const float* __restrict__ bn_m,
    const float* __restrict__ bn_v, const float* __restrict__ x,
    float* __restrict__ out) {
  __shared__ ushort yl[32 * 136];  // 8.5 KB
  int t = threadIdx.x;
  int n = blockIdx.y;
  int l0 = blockIdx.x * 32;
  float mu = st[n] * (1.f / DOUT);
  float rs = rsqrtf(st[32 + n] * (1.f / DOUT) - mu * mu + EPSF);

  {
    int l = t & 31, og = t >> 5;  // 8 o-groups of 16
    const float* h2n = h2 + (size_t)n * DOUT;
#pragma unroll
    for (int half = 0; half < 2; half++) {
      float y[8];
#pragma unroll
      for (int jj = 0; jj < 8; jj++) {
        int o = og * 16 + half * 8 + jj;
        int d = o * LL + l0 + l;
        y[jj] = (h2n[d] - mu) * rs * g2[d] + b2[d];
      }
      union { short8 s; unsigned u[4]; } p;
      p.u[0] = bfp2(y[0], y[1]);
      p.u[1] = bfp2(y[2], y[3]);
      p.u[2] = bfp2(y[4], y[5]);
      p.u[3] = bfp2(y[6], y[7]);
      *(short8*)&yl[l * 136 + og * 16 + half * 8] = p.s;
    }
  }
  __syncthreads();

  int lane = t & 63, wv = t >> 6;
  int m16 = lane & 15, kg = lane >> 4;
  f32x4 acc[4][2];
#pragma unroll
  for (int ms = 0; ms < 4; ms++)
#pragma unroll
    for (int ls = 0; ls < 2; ls++) acc[ms][ls] = (f32x4){0.f, 0.f, 0.f, 0.f};

#pragma unroll
  for (int kc = 0; kc < 4; kc++) {
    short8 b[2];
#pragma unroll
    for (int ls = 0; ls < 2; ls++)
      b[ls] = *(const short8*)&yl[(ls * 16 + m16) * 136 + kc * 32 + kg * 8];
#pragma unroll
    for (int ms = 0; ms < 4; ms++) {
      short8 a = *(const short8*)(wobf +
          (((wv * 64 + ms * 16 + m16) << 7) + kc * 32 + kg * 8));
#pragma unroll
      for (int ls = 0; ls < 2; ls++)
        acc[ms][ls] =
            __builtin_amdgcn_mfma_f32_16x16x32_bf16(a, b[ls], acc[ms][ls], 0, 0, 0);
    }
  }

#pragma unroll
  for (int ms = 0; ms < 4; ms++)
#pragma unroll
    for (int r = 0; r < 4; r++) {
      int O = wv * 64 + ms * 16 + kg * 4 + r;
      float sc = bn_g[O] * rsqrtf(bn_v[O] + EPSF);
      float sh = bn_b[O] - bn_m[O] * sc;
#pragma unroll
      for (int ls = 0; ls < 2; ls++) {
        int col = l0 + ls * 16 + m16;
        size_t base = ((size_t)(n * CC + O)) * LL + col;
        out[base] = acc[ms][ls][r] * sc + sh + x[base];
      }
    }
}

extern "C" void kernel_launch(void* const* d_in, const int* in_sizes, int n_in,
                              void* d_out, int out_size, void* d_ws,
                              size_t ws_size, hipStream_t stream) {
  const float* x = (const float*)d_in[0];
  const float* wq = (const float*)d_in[1];
  const float* wk = (const float*)d_in[2];
  const float* gamma1 = (const float*)d_in[3];
  const float* beta1 = (const float*)d_in[4];
  const float* w1 = (const float*)d_in[5];
  const float* b1 = (const float*)d_in[6];
  const float* w2 = (const float*)d_in[7];
  const float* b2 = (const float*)d_in[8];
  const float* gamma2 = (const float*)d_in[9];
  const float* beta2 = (const float*)d_in[10];
  const float* w_out = (const float*)d_in[11];
  const float* bn_g = (const float*)d_in[12];
  const float* bn_b = (const float*)d_in[13];
  const float* bn_m = (const float*)d_in[14];
  const float* bn_v = (const float*)d_in[15];
  float* outp = (float*)d_out;
  float* ws = (float*)d_ws;

  // ws layout (floats): q(4194304) | k(4194304) | f(294912) | st(64) |
  //   h1bf(4096) | wqkbf(32768) | wobf(16384). h2 aliases q.
  float* qb = ws;
  float* kb = ws + 4194304;
  float* fb = ws + 8388608;
  float* stb = ws + 8683520;
  ushort* h1bfb = (ushort*)(ws + 8683584);
  ushort* wqkbfb = (ushort*)(ws + 8687680);
  ushort* wobfb = (ushort*)(ws + 8720448);
  float* h2b = qb;

  if (ws_size < 8736832ull * sizeof(float)) return;  // fail visibly

  // k_wcvt converts weights AND zeroes f+st (memset dispatch absorbed)
  k_wcvt<<<dim3(385), 256, 0, stream>>>(wq, wk, w_out, wqkbfb, wobfb, fb);
  k_qkx<<<dim3(16, 32), 256, 0, stream>>>(x, wqkbfb, qb, kb);
  k_attn<<<dim3(32, 4, 4), 256, 0, stream>>>(qb, kb, fb);
  k_ln1<<<dim3(32), 256, 0, stream>>>(fb, gamma1, beta1);
  k_ffn1<<<dim3(256, 2), 256, 0, stream>>>(fb, w1, b1, h1bfb);
  k_ffn2<<<dim3(1024), 256, 0, stream>>>(h1bfb, w2, b2, h2b, stb);
  k_out<<<dim3(32, 32), 256, 0, stream>>>(h2b, stb, gamma2, beta2, wobfb,
                                          bn_g, bn_b, bn_m, bn_v, x, outp);
}

// Round 10
// 336.215 us; speedup vs baseline: 1.0263x; 1.0204x over previous
//
#include <hip/hip_runtime.h>

#define NN 32
#define CC 256
#define LL 1024
#define IC 128
#define DA 9216
#define DOUT 131072
#define EPSF 1e-5f

typedef __attribute__((ext_vector_type(8))) short short8;
typedef __attribute__((ext_vector_type(4))) float f32x4;

__device__ __forceinline__ ushort bf_rne(float f) {
  union { float f; unsigned u; } v;
  v.f = f;
  unsigned u = v.u;
  u += 0x7FFF + ((u >> 16) & 1);
  return (ushort)(u >> 16);
}

__device__ __forceinline__ float bf2f(ushort u) {
  union { float f; unsigned v; } x;
  x.v = ((unsigned)u) << 16;
  return x.f;
}

// pack two fp32 -> packed bf16 pair (lo in [15:0], hi in [31:16]).
__device__ __forceinline__ unsigned bfp2(float lo, float hi) {
  union { float f; unsigned u; } a, b;
  a.f = lo; b.f = hi;
  return __builtin_amdgcn_perm(b.u + 0x8000u, a.u + 0x8000u, 0x07060302u);
}

// ------- K_wcvt: wq|wk|wo -> bf16, w1 -> bf16, zero st. Grid 2401. ----------
__global__ __launch_bounds__(256) void k_wcvt(const float* __restrict__ wq,
                                              const float* __restrict__ wk,
                                              const float* __restrict__ wo,
                                              const float* __restrict__ w1,
                                              ushort* __restrict__ wqkbf,
                                              ushort* __restrict__ wobf,
                                              ushort* __restrict__ w1bf,
                                              float* __restrict__ st) {
  int b = blockIdx.x;
  if (b < 96) {
    int idx = (b * 256 + threadIdx.x) * 4;  // 98304 small-weight elems
    float4 v;
    if (idx < 32768) v = *(const float4*)(wq + idx);
    else if (idx < 65536) v = *(const float4*)(wk + idx - 32768);
    else v = *(const float4*)(wo + idx - 65536);
    uint2 o;
    o.x = bfp2(v.x, v.y);
    o.y = bfp2(v.z, v.w);
    if (idx < 65536) *(uint2*)(wqkbf + idx) = o;
    else *(uint2*)(wobf + idx - 65536) = o;
  } else if (b < 2400) {
    int idx = ((b - 96) * 256 + threadIdx.x) * 4;  // w1: 2359296 elems
    float4 v = *(const float4*)(w1 + idx);
    uint2 o;
    o.x = bfp2(v.x, v.y);
    o.y = bfp2(v.z, v.w);
    *(uint2*)(w1bf + idx) = o;
  } else {
    if (threadIdx.x < 64) st[threadIdx.x] = 0.f;
  }
}

// ---------------- K_qkx: fused transpose + q/k MFMA (unchanged) -------------
__global__ __launch_bounds__(256, 4) void k_qkx(const float* __restrict__ x,
                                                const ushort* __restrict__ wqkbf,
                                                float* __restrict__ q,
                                                float* __restrict__ k) {
  __shared__ ushort xl[64 * 264];  // 33.8 KB
  int t = threadIdx.x;
  int n = blockIdx.y;
  int l0 = blockIdx.x * 64;
  int lane = t & 63, wv = t >> 6;
  int m16 = lane & 15, kg = lane >> 4;

  {
    int l = t & 63, g = t >> 6;
    const float* xn = x + ((size_t)n * CC) * LL + l0 + l;
#pragma unroll
    for (int i = 0; i < 8; i++) {
      int c8 = (i * 4 + g) * 8;
      float v[8];
#pragma unroll
      for (int j = 0; j < 8; j++) v[j] = xn[(size_t)(c8 + j) * LL];
      union { short8 s; unsigned u[4]; } p;
      p.u[0] = bfp2(v[0], v[1]);
      p.u[1] = bfp2(v[2], v[3]);
      p.u[2] = bfp2(v[4], v[5]);
      p.u[3] = bfp2(v[6], v[7]);
      *(short8*)&xl[l * 264 + c8] = p.s;
    }
  }
  __syncthreads();

  f32x4 acc[2][2][4];
#pragma unroll
  for (int mt = 0; mt < 2; mt++)
#pragma unroll
    for (int ms = 0; ms < 2; ms++)
#pragma unroll
      for (int ls = 0; ls < 4; ls++) acc[mt][ms][ls] = (f32x4){0.f, 0.f, 0.f, 0.f};

#pragma unroll
  for (int kc = 0; kc < 8; kc++) {
    short8 a[2][2];
#pragma unroll
    for (int mt = 0; mt < 2; mt++)
#pragma unroll
      for (int ms = 0; ms < 2; ms++)
        a[mt][ms] = *(const short8*)(wqkbf +
            (((mt * 128 + wv * 32 + ms * 16 + m16) << 8) + kc * 32 + kg * 8));
#pragma unroll
    for (int ls = 0; ls < 4; ls++) {
      short8 b = *(const short8*)&xl[(ls * 16 + m16) * 264 + kc * 32 + kg * 8];
      acc[0][0][ls] =
          __builtin_amdgcn_mfma_f32_16x16x32_bf16(a[0][0], b, acc[0][0][ls], 0, 0, 0);
      acc[0][1][ls] =
          __builtin_amdgcn_mfma_f32_16x16x32_bf16(a[0][1], b, acc[0][1][ls], 0, 0, 0);
      acc[1][0][ls] =
          __builtin_amdgcn_mfma_f32_16x16x32_bf16(a[1][0], b, acc[1][0][ls], 0, 0, 0);
      acc[1][1][ls] =
          __builtin_amdgcn_mfma_f32_16x16x32_bf16(a[1][1], b, acc[1][1][ls], 0, 0, 0);
    }
  }

#pragma unroll
  for (int mt = 0; mt < 2; mt++) {
    float* outp = (mt ? k : q) + (size_t)n * IC * LL;
#pragma unroll
    for (int ms = 0; ms < 2; ms++)
#pragma unroll
      for (int ls = 0; ls < 4; ls++) {
        int col = l0 + ls * 16 + m16;
#pragma unroll
        for (int r = 0; r < 4; r++)
          outp[(size_t)(wv * 32 + ms * 16 + kg * 4 + r) * LL + col] =
              acc[mt][ms][ls][r];
      }
  }
}

// ------- K2: attn scores -> PLAIN partial stores (atomics removed) ----------
// f_part[c0blk][n][r*LL+l] = 2*acc; each element written exactly once.
__global__ __launch_bounds__(256) void k_attn(const float* __restrict__ q,
                                              const float* __restrict__ k,
                                              float* __restrict__ f_part) {
  int n = blockIdx.x;
  int c0b = blockIdx.y;
  int c0 = c0b * 32;
  int l = blockIdx.z * 256 + threadIdx.x;
  int h = l >> 5, w = l & 31;
  const float* qn = q + (size_t)n * IC * LL;
  const float* kn = k + (size_t)n * IC * LL;
  bool val[9];
  int off[9];
#pragma unroll
  for (int i = 0; i < 3; i++)
#pragma unroll
    for (int j = 0; j < 3; j++) {
      int r = i * 3 + j;
      int hh = h + i - 1, ww = w + j - 1;
      val[r] = (hh >= 0 && hh < 32 && ww >= 0 && ww < 32);
      off[r] = hh * 32 + ww;
    }
  float acc[9];
#pragma unroll
  for (int r = 0; r < 9; r++) acc[r] = 0.f;
#pragma unroll 4
  for (int cc = 0; cc < 32; cc++) {
    int c = c0 + cc;
    float qv = qn[c * LL + l];
    const float* kc = kn + c * LL;
#pragma unroll
    for (int r = 0; r < 9; r++) {
      float kv = val[r] ? kc[off[r]] : 0.f;
      acc[r] += qv * kv;
    }
  }
  float* dst = f_part + ((size_t)(c0b * 32 + n)) * DA;
#pragma unroll
  for (int r = 0; r < 9; r++) dst[r * LL + l] = 2.f * acc[r];
}

// ------- K3: sum 4 partials, LayerNorm over 9216, emit bf16 fln -------------
__global__ __launch_bounds__(256) void k_ln1(const float* __restrict__ f_part,
                                             const float* __restrict__ g1,
                                             const float* __restrict__ b1,
                                             ushort* __restrict__ flnbf) {
  int n = blockIdx.x, t = threadIdx.x;
  float4 v[9];
  float s = 0.f, ss = 0.f;
#pragma unroll
  for (int kk = 0; kk < 9; kk++) {
    int e4 = t + kk * 256;
    float4 a = ((const float4*)(f_part + ((size_t)(0 * 32 + n)) * DA))[e4];
    float4 b = ((const float4*)(f_part + ((size_t)(1 * 32 + n)) * DA))[e4];
    float4 c = ((const float4*)(f_part + ((size_t)(2 * 32 + n)) * DA))[e4];
    float4 d = ((const float4*)(f_part + ((size_t)(3 * 32 + n)) * DA))[e4];
    float4 o;
    o.x = a.x + b.x + c.x + d.x;
    o.y = a.y + b.y + c.y + d.y;
    o.z = a.z + b.z + c.z + d.z;
    o.w = a.w + b.w + c.w + d.w;
    v[kk] = o;
    s += o.x + o.y + o.z + o.w;
    ss += o.x * o.x + o.y * o.y + o.z * o.z + o.w * o.w;
  }
#pragma unroll
  for (int o = 32; o; o >>= 1) {
    s += __shfl_down(s, o);
    ss += __shfl_down(ss, o);
  }
  __shared__ float ps[4], pss[4], stats[2];
  int wid = t >> 6, lid = t & 63;
  if (lid == 0) { ps[wid] = s; pss[wid] = ss; }
  __syncthreads();
  if (t == 0) {
    float S = ps[0] + ps[1] + ps[2] + ps[3];
    float SS = pss[0] + pss[1] + pss[2] + pss[3];
    float mu = S / DA;
    float var = SS / DA - mu * mu;
    stats[0] = mu;
    stats[1] = rsqrtf(var + EPSF);
  }
  __syncthreads();
  float mu = stats[0], rs = stats[1];
  ushort* fln = flnbf + (size_t)n * DA;
#pragma unroll
  for (int kk = 0; kk < 9; kk++) {
    int e4 = t + kk * 256;
    float4 g = ((const float4*)g1)[e4];
    float4 b = ((const float4*)b1)[e4];
    float4 o;
    o.x = (v[kk].x - mu) * rs * g.x + b.x;
    o.y = (v[kk].y - mu) * rs * g.y + b.y;
    o.z = (v[kk].z - mu) * rs * g.z + b.z;
    o.w = (v[kk].w - mu) * rs * g.w + b.w;
    uint2 p;
    p.x = bfp2(o.x, o.y);
    p.y = bfp2(o.z, o.w);
    *(uint2*)(fln + e4 * 4) = p;
  }
}

// ------- K4: h1 = relu(fln @ w1^T + b1) -> bf16; bf16 inputs (half bytes) ---
__global__ __launch_bounds__(256) void k_ffn1(const ushort* __restrict__ flnbf,
                                              const ushort* __restrict__ w1bf,
                                              const float* __restrict__ b1,
                                              ushort* __restrict__ h1bf) {
  int o = blockIdx.x, nsb = blockIdx.y * 16, t = threadIdx.x;
  float acc[16];
#pragma unroll
  for (int i = 0; i < 16; i++) acc[i] = 0.f;
  const ushort* w1r = w1bf + (size_t)o * DA;
  for (int kk = 0; kk < 9; kk++) {
    int e = kk * 1024 + t * 4;
    ushort4 wu = *(const ushort4*)(w1r + e);
    float w0 = bf2f(wu.x), w1v = bf2f(wu.y), w2v = bf2f(wu.z), w3 = bf2f(wu.w);
#pragma unroll
    for (int i = 0; i < 16; i++) {
      ushort4 fu = *(const ushort4*)(flnbf + (size_t)(nsb + i) * DA + e);
      acc[i] += w0 * bf2f(fu.x) + w1v * bf2f(fu.y) + w2v * bf2f(fu.z) +
                w3 * bf2f(fu.w);
    }
  }
#pragma unroll
  for (int i = 0; i < 16; i++)
#pragma unroll
    for (int s = 32; s; s >>= 1) acc[i] += __shfl_down(acc[i], s);
  __shared__ float part[4][16];
  int wid = t >> 6, lid = t & 63;
  if (lid == 0) {
#pragma unroll
    for (int i = 0; i < 16; i++) part[wid][i] = acc[i];
  }
  __syncthreads();
  if (t < 16) {
    float sum = part[0][t] + part[1][t] + part[2][t] + part[3][t] + b1[o];
    h1bf[(size_t)(nsb + t) * CC + o] = bf_rne(fmaxf(sum, 0.f));
  }
}

// ------- K5: h2(bf16) = h1 @ w2^T + b2 via MFMA; deep staging ---------------
// All 32 staging loads issued before any convert (max in-flight); LDS tile
// 66 KB, 2 blocks/CU. h2 stored bf16 (halves write+k_out read). Stats fp32.
__global__ __launch_bounds__(256, 2) void k_ffn2(
    const ushort* __restrict__ h1bf, const float* __restrict__ w2,
    const float* __restrict__ b2, ushort* __restrict__ h2u,
    float* __restrict__ st) {
  __shared__ ushort wt[128 * 264];  // 66 KB
  __shared__ float bs[64];
  int t = threadIdx.x;
  int j0 = blockIdx.x * 128;
  if (t < 64) bs[t] = 0.f;

  // stage: 32 float4 loads ALL in flight, then convert+write
  {
    const float* wsrc = w2 + (size_t)j0 * CC;
    int row_t = t >> 6;
    int col_t = (t & 63) * 4;
    float4 v[32];
#pragma unroll
    for (int u = 0; u < 32; u++)
      v[u] = *(const float4*)(wsrc + (size_t)u * 1024 + t * 4);
#pragma unroll
    for (int u = 0; u < 32; u++) {
      int row = u * 4 + row_t;
      uint2 p;
      p.x = bfp2(v[u].x, v[u].y);
      p.y = bfp2(v[u].z, v[u].w);
      *(uint2*)&wt[row * 264 + col_t] = p;
    }
  }
  __syncthreads();  // wt ready; bs zero visible

  int lane = t & 63, wv = t >> 6;
  int m16 = lane & 15, kg = lane >> 4;
  int jw = j0 + wv * 32;
  int j[2] = {jw + m16, jw + 16 + m16};

  f32x4 acc[2][2];
#pragma unroll
  for (int m = 0; m < 2; m++)
#pragma unroll
    for (int nn = 0; nn < 2; nn++) acc[m][nn] = (f32x4){0.f, 0.f, 0.f, 0.f};

#pragma unroll
  for (int kc = 0; kc < 8; kc++) {
    short8 a0 = *(const short8*)(h1bf + m16 * CC + kc * 32 + kg * 8);
    short8 a1 = *(const short8*)(h1bf + (16 + m16) * CC + kc * 32 + kg * 8);
#pragma unroll
    for (int nn = 0; nn < 2; nn++) {
      short8 b = *(const short8*)&wt[(wv * 32 + nn * 16 + m16) * 264 +
                                     kc * 32 + kg * 8];
      acc[0][nn] =
          __builtin_amdgcn_mfma_f32_16x16x32_bf16(a0, b, acc[0][nn], 0, 0, 0);
      acc[1][nn] =
          __builtin_amdgcn_mfma_f32_16x16x32_bf16(a1, b, acc[1][nn], 0, 0, 0);
    }
  }

  float b2v[2] = {b2[j[0]], b2[j[1]]};

  float s8[2][4], q8[2][4];
#pragma unroll
  for (int m = 0; m < 2; m++)
#pragma unroll
    for (int r = 0; r < 4; r++) { s8[m][r] = 0.f; q8[m][r] = 0.f; }
#pragma unroll
  for (int m = 0; m < 2; m++)
#pragma unroll
    for (int nn = 0; nn < 2; nn++) {
#pragma unroll
      for (int r = 0; r < 4; r++) {
        float v = acc[m][nn][r] + b2v[nn];
        int row = m * 16 + kg * 4 + r;
        h2u[(size_t)row * DOUT + j[nn]] = bf_rne(v);
        s8[m][r] += v;
        q8[m][r] += v * v;
      }
    }
#pragma unroll
  for (int off = 8; off; off >>= 1)
#pragma unroll
    for (int m = 0; m < 2; m++)
#pragma unroll
      for (int r = 0; r < 4; r++) {
        s8[m][r] += __shfl_down(s8[m][r], off, 16);
        q8[m][r] += __shfl_down(q8[m][r], off, 16);
      }
  if (m16 == 0) {
#pragma unroll
    for (int m = 0; m < 2; m++)
#pragma unroll
      for (int r = 0; r < 4; r++) {
        int row = m * 16 + kg * 4 + r;
        atomicAdd(&bs[row], s8[m][r]);
        atomicAdd(&bs[32 + row], q8[m][r]);
      }
  }
  __syncthreads();
  if (t < 64) atomicAdd(&st[t], bs[t]);
}

// ------- K7: out = BN(LN2(h2)*g2+b2 @ w_out^T) + x; h2 read as bf16 ---------
__global__ __launch_bounds__(256, 4) void k_out(
    const ushort* __restrict__ h2u, const float* __restrict__ st,
    const float* __restrict__ g2, const float* __restrict__ b2,
    const ushort* __restrict__ wobf, const float* __restrict__ bn_g,
    const float* __restrict__ bn_b, const float* __restrict__ bn_m,
    const float* __restrict__ bn_v, const float* __restrict__ x,
    float* __restrict__ out) {
  __shared__ ushort yl[32 * 136];  // 8.5 KB
  int t = threadIdx.x;
  int n = blockIdx.y;
  int l0 = blockIdx.x * 32;
  float mu = st[n] * (1.f / DOUT);
  float rs = rsqrtf(st[32 + n] * (1.f / DOUT) - mu * mu + EPSF);

  {
    int l = t & 31, og = t >> 5;  // 8 o-groups of 16
    const ushort* h2n = h2u + (size_t)n * DOUT;
#pragma unroll
    for (int half = 0; half < 2; half++) {
      float y[8];
#pragma unroll
      for (int jj = 0; jj < 8; jj++) {
        int o = og * 16 + half * 8 + jj;
        int d = o * LL + l0 + l;
        y[jj] = (bf2f(h2n[d]) - mu) * rs * g2[d] + b2[d];
      }
      union { short8 s; unsigned u[4]; } p;
      p.u[0] = bfp2(y[0], y[1]);
      p.u[1] = bfp2(y[2], y[3]);
      p.u[2] = bfp2(y[4], y[5]);
      p.u[3] = bfp2(y[6], y[7]);
      *(short8*)&yl[l * 136 + og * 16 + half * 8] = p.s;
    }
  }
  __syncthreads();

  int lane = t & 63, wv = t >> 6;
  int m16 = lane & 15, kg = lane >> 4;
  f32x4 acc[4][2];
#pragma unroll
  for (int ms = 0; ms < 4; ms++)
#pragma unroll
    for (int ls = 0; ls < 2; ls++) acc[ms][ls] = (f32x4){0.f, 0.f, 0.f, 0.f};

#pragma unroll
  for (int kc = 0; kc < 4; kc++) {
    short8 b[2];
#pragma unroll
    for (int ls = 0; ls < 2; ls++)
      b[ls] = *(const short8*)&yl[(ls * 16 + m16) * 136 + kc * 32 + kg * 8];
#pragma unroll
    for (int ms = 0; ms < 4; ms++) {
      short8 a = *(const short8*)(wobf +
          (((wv * 64 + ms * 16 + m16) << 7) + kc * 32 + kg * 8));
#pragma unroll
      for (int ls = 0; ls < 2; ls++)
        acc[ms][ls] =
            __builtin_amdgcn_mfma_f32_16x16x32_bf16(a, b[ls], acc[ms][ls], 0, 0, 0);
    }
  }

#pragma unroll
  for (int ms = 0; ms < 4; ms++)
#pragma unroll
    for (int r = 0; r < 4; r++) {
      int O = wv * 64 + ms * 16 + kg * 4 + r;
      float sc = bn_g[O] * rsqrtf(bn_v[O] + EPSF);
      float sh = bn_b[O] - bn_m[O] * sc;
#pragma unroll
      for (int ls = 0; ls < 2; ls++) {
        int col = l0 + ls * 16 + m16;
        size_t base = ((size_t)(n * CC + O)) * LL + col;
        out[base] = acc[ms][ls][r] * sc + sh + x[base];
      }
    }
}

extern "C" void kernel_launch(void* const* d_in, const int* in_sizes, int n_in,
                              void* d_out, int out_size, void* d_ws,
                              size_t ws_size, hipStream_t stream) {
  const float* x = (const float*)d_in[0];
  const float* wq = (const float*)d_in[1];
  const float* wk = (const float*)d_in[2];
  const float* gamma1 = (const float*)d_in[3];
  const float* beta1 = (const float*)d_in[4];
  const float* w1 = (const float*)d_in[5];
  const float* b1 = (const float*)d_in[6];
  const float* w2 = (const float*)d_in[7];
  const float* b2 = (const float*)d_in[8];
  const float* gamma2 = (const float*)d_in[9];
  const float* beta2 = (const float*)d_in[10];
  const float* w_out = (const float*)d_in[11];
  const float* bn_g = (const float*)d_in[12];
  const float* bn_b = (const float*)d_in[13];
  const float* bn_m = (const float*)d_in[14];
  const float* bn_v = (const float*)d_in[15];
  float* outp = (float*)d_out;
  float* ws = (float*)d_ws;

  // ws layout (float offsets):
  //   q 0 (4194304) | k 4194304 (4194304) | f_part 8388608 (1179648) |
  //   st 9568256 (64) | h1bf 9568320 (4096 fl = 8192 us) |
  //   flnbf 9572416 (147456 fl = 294912 us) | wqkbf 9719872 (32768 fl) |
  //   wobf 9752640 (16384 fl) | w1bf 9769024 (1179648 fl = 2359296 us).
  //   h2u aliases q (needs 2097152 fl).
  float* qb = ws;
  float* kb = ws + 4194304;
  float* fpart = ws + 8388608;
  float* stb = ws + 9568256;
  ushort* h1bfb = (ushort*)(ws + 9568320);
  ushort* flnbfb = (ushort*)(ws + 9572416);
  ushort* wqkbfb = (ushort*)(ws + 9719872);
  ushort* wobfb = (ushort*)(ws + 9752640);
  ushort* w1bfb = (ushort*)(ws + 9769024);
  ushort* h2ub = (ushort*)qb;

  if (ws_size < 10948672ull * sizeof(float)) return;  // fail visibly

  k_wcvt<<<dim3(2401), 256, 0, stream>>>(wq, wk, w_out, w1, wqkbfb, wobfb,
                                         w1bfb, stb);
  k_qkx<<<dim3(16, 32), 256, 0, stream>>>(x, wqkbfb, qb, kb);
  k_attn<<<dim3(32, 4, 4), 256, 0, stream>>>(qb, kb, fpart);
  k_ln1<<<dim3(32), 256, 0, stream>>>(fpart, gamma1, beta1, flnbfb);
  k_ffn1<<<dim3(256, 2), 256, 0, stream>>>(flnbfb, w1bfb, b1, h1bfb);
  k_ffn2<<<dim3(1024), 256, 0, stream>>>(h1bfb, w2, b2, h2ub, stb);
  k_out<<<dim3(32, 32), 256, 0, stream>>>(h2ub, stb, gamma2, beta2, wobfb,
                                          bn_g, bn_b, bn_m, bn_v, x, outp);
}